// Round 3
// baseline (1180.361 us; speedup 1.0000x reference)
//
#include <hip/hip_runtime.h>

// Diagnostic-grade scalar fused kernel: settles input dtype (bf16 vs fp32) at
// runtime and validates all op semantics. No MFMA, LDS = 56 KB (< 64 KB).
// Perf target for THIS round is only "correct + measurable"; MFMA returns next.

typedef unsigned short u16;

__device__ __forceinline__ float bf2f(u16 u) {
    union { unsigned int i; float f; } w; w.i = ((unsigned int)u) << 16; return w.f;
}
__device__ __forceinline__ u16 f2bf(float f) {
    union { float f; unsigned int i; } w; w.f = f;
    unsigned int r = w.i + 0x7fffu + ((w.i >> 16) & 1u);   // RNE
    return (u16)(r >> 16);
}

template<int F32>
__device__ __forceinline__ float ldv(const void* p, int i) {
    if (F32) return ((const float*)p)[i];
    return bf2f(((const u16*)p)[i]);
}

// One block = one batch row n. 256 threads; thread == channel index.
// Buffers ping-pong: S1 hA=x+pe; S2 hB=G(hA); S3 hA=lrelu(w1*hB+b1);
// S4 hB=G(hA); S5 hA=lrelu(w2*hB+b2); S6 out=wp*hA+bp.
template<int F32>
__device__ void block_body(const void* xv, const void* Av,
                           const void* w1v, const void* b1v,
                           const void* w2v, const void* b2v,
                           const void* wpv, const void* bpv,
                           int t0, void* outv,
                           float (*hA)[26], float (*hB)[26], float (*Al)[26])
{
    const int tid = threadIdx.x;          // 0..255
    const int n   = blockIdx.x;           // 0..4095

    // A matrix -> LDS (fp32)
    for (int i = tid; i < 625; i += 256) Al[i / 25][i % 25] = ldv<F32>(Av, i);

    // ---- S1: hA[c][v] = x[n,c,v] + pe[t0 + (n%64)][c]
    {
        const int c = tid;
        float freq = expf(-0.0719557847738304f * (float)(c >> 1)); // -2*ln(1e4)/256
        float ang  = (float)(t0 + (n & 63)) * freq;
        float pe   = (c & 1) ? cosf(ang) : sinf(ang);
        const int base = n * 6400 + c * 25;
        #pragma unroll
        for (int v = 0; v < 25; v++) hA[c][v] = ldv<F32>(xv, base + v) + pe;
    }
    __syncthreads();

    // ---- S2: hB[c][v] = sum_u Al[v][u] * hA[c][u]
    {
        const int c = tid;
        float hr[25];
        #pragma unroll
        for (int u = 0; u < 25; u++) hr[u] = hA[c][u];
        for (int v = 0; v < 25; v++) {
            float s = 0.f;
            #pragma unroll
            for (int u = 0; u < 25; u++) s += Al[v][u] * hr[u];
            hB[c][v] = s;
        }
    }
    __syncthreads();

    // ---- S3: hA[o][v] = lrelu( b1[o] + sum_c w1[o,c] * hB[c][v] )
    {
        const int o = tid;
        float acc[25];
        float b = ldv<F32>(b1v, o);
        #pragma unroll
        for (int v = 0; v < 25; v++) acc[v] = b;
        for (int c = 0; c < 256; c++) {
            float wv = ldv<F32>(w1v, o * 256 + c);
            #pragma unroll
            for (int v = 0; v < 25; v++) acc[v] += wv * hB[c][v];   // LDS broadcast
        }
        #pragma unroll
        for (int v = 0; v < 25; v++) {
            float y = acc[v];
            hA[o][v] = (y >= 0.f) ? y : 0.01f * y;
        }
    }
    __syncthreads();

    // ---- S4: hB = G(hA)
    {
        const int c = tid;
        float hr[25];
        #pragma unroll
        for (int u = 0; u < 25; u++) hr[u] = hA[c][u];
        for (int v = 0; v < 25; v++) {
            float s = 0.f;
            #pragma unroll
            for (int u = 0; u < 25; u++) s += Al[v][u] * hr[u];
            hB[c][v] = s;
        }
    }
    __syncthreads();

    // ---- S5: hA[o][v] = lrelu( b2[o] + sum_c w2[o,c] * hB[c][v] )
    {
        const int o = tid;
        float acc[25];
        float b = ldv<F32>(b2v, o);
        #pragma unroll
        for (int v = 0; v < 25; v++) acc[v] = b;
        for (int c = 0; c < 256; c++) {
            float wv = ldv<F32>(w2v, o * 256 + c);
            #pragma unroll
            for (int v = 0; v < 25; v++) acc[v] += wv * hB[c][v];
        }
        #pragma unroll
        for (int v = 0; v < 25; v++) {
            float y = acc[v];
            hA[o][v] = (y >= 0.f) ? y : 0.01f * y;
        }
    }
    __syncthreads();

    // ---- S6: out[n,o,v] = bp[o] + sum_c wp[o,c] * hA[c][v]
    {
        const int o = tid;
        float acc[25];
        float b = ldv<F32>(bpv, o);
        #pragma unroll
        for (int v = 0; v < 25; v++) acc[v] = b;
        for (int c = 0; c < 256; c++) {
            float wv = ldv<F32>(wpv, o * 256 + c);
            #pragma unroll
            for (int v = 0; v < 25; v++) acc[v] += wv * hA[c][v];
        }
        const int base = n * 6400 + o * 25;
        if (F32) {
            float* of = (float*)outv;
            #pragma unroll
            for (int v = 0; v < 25; v++) of[base + v] = acc[v];
        } else {
            u16* oh = (u16*)outv;
            #pragma unroll
            for (int v = 0; v < 25; v++) oh[base + v] = f2bf(acc[v]);
        }
    }
}

__global__ void __launch_bounds__(256)
ode_scalar(const void* xv, const void* Av, const void* w1v, const void* b1v,
           const void* w2v, const void* b2v, const void* wpv, const void* bpv,
           const int* tptr, void* outv)
{
    __shared__ float hA[256][26];   // +1 col pad vs 25 (bank spread); 26.6 KB
    __shared__ float hB[256][26];
    __shared__ float Al[25][26];

    // ---- runtime dtype probe on w1 (uniform across all threads/blocks):
    // bf16 data: low u16 of each word is a bf16 with |w|<=1/16 -> exp field <= 0x7B.
    // fp32 data: low u16 = mantissa bits, ~uniform -> ~44% have exp field >= 0x90.
    const unsigned int* wu = (const unsigned int*)w1v;
    int cnt = 0;
    for (int i = 0; i < 128; i++) {
        unsigned int e = (wu[i] >> 7) & 0xFFu;
        cnt += (e >= 0x90u) ? 1 : 0;
    }
    const int t0 = tptr[0];
    if (cnt > 8)
        block_body<1>(xv, Av, w1v, b1v, w2v, b2v, wpv, bpv, t0, outv, hA, hB, Al);
    else
        block_body<0>(xv, Av, w1v, b1v, w2v, b2v, wpv, bpv, t0, outv, hA, hB, Al);
}

extern "C" void kernel_launch(void* const* d_in, const int* in_sizes, int n_in,
                              void* d_out, int out_size, void* d_ws, size_t ws_size,
                              hipStream_t stream)
{
    const void* x  = d_in[0];
    const void* A  = d_in[1];
    const void* w1 = d_in[2];
    const void* b1 = d_in[3];
    const void* w2 = d_in[4];
    const void* b2 = d_in[5];
    const void* wp = d_in[6];
    const void* bp = d_in[7];
    const int*  t  = (const int*)d_in[8];
    (void)in_sizes; (void)n_in; (void)out_size; (void)d_ws; (void)ws_size;
    ode_scalar<<<4096, 256, 0, stream>>>(x, A, w1, b1, w2, b2, wp, bp, t, d_out);
}